// Round 10
// baseline (404.753 us; speedup 1.0000x reference)
//
#include <hip/hip_runtime.h>
#include <hip/hip_bf16.h>
#include <math.h>

#define NEG_SLOPE 0.2f
#define SCAN_BLOCK 256
#define BK 32
#define LOG2E 1.4426950408889634f

__device__ __forceinline__ unsigned pack_bf16_pair(float lo, float hi) {
    unsigned ul = __float_as_uint(lo);
    ul += 0x7fffu + ((ul >> 16) & 1u);          // RNE
    unsigned uh = __float_as_uint(hi);
    uh += 0x7fffu + ((uh >> 16) & 1u);
    return (ul >> 16) | (uh & 0xffff0000u);
}

// ---------------- utility ----------------
__global__ __launch_bounds__(256) void zero_int_kernel(int* __restrict__ p, int n) {
    int i = blockIdx.x * 256 + threadIdx.x;
    if (i < n) p[i] = 0;
}

// ---------------- CSR build ----------------
__global__ __launch_bounds__(256) void count_deg_kernel(const int* __restrict__ dst,
                                                        int E, int N, int* __restrict__ deg) {
    int e = blockIdx.x * 256 + threadIdx.x;
    int Etot = E + N;
    if (e >= Etot) return;
    int d = (e < E) ? dst[e] : (e - E);
    atomicAdd(&deg[d], 1);
}

__global__ __launch_bounds__(SCAN_BLOCK) void deg_partial_kernel(const int* __restrict__ deg,
                                                                 int* __restrict__ part, int N) {
    __shared__ int red[SCAN_BLOCK];
    int t = threadIdx.x;
    int i = blockIdx.x * SCAN_BLOCK + t;
    red[t] = (i < N) ? deg[i] : 0;
    __syncthreads();
    #pragma unroll
    for (int off = SCAN_BLOCK / 2; off > 0; off >>= 1) {
        if (t < off) red[t] += red[t + off];
        __syncthreads();
    }
    if (t == 0) part[blockIdx.x] = red[0];
}

__global__ __launch_bounds__(1024) void scan_part_kernel(int* __restrict__ part, int nPart) {
    __shared__ int s[1024];
    int t = threadIdx.x;
    int v = (t < nPart) ? part[t] : 0;
    s[t] = v;
    __syncthreads();
    for (int off = 1; off < 1024; off <<= 1) {
        int u = (t >= off) ? s[t - off] : 0;
        __syncthreads();
        s[t] += u;
        __syncthreads();
    }
    if (t < nPart) part[t] = (t == 0) ? 0 : s[t - 1];   // exclusive block offsets
}

__global__ __launch_bounds__(SCAN_BLOCK) void scan_final_kernel(const int* __restrict__ deg,
                                                                const int* __restrict__ part,
                                                                int* __restrict__ row_ptr, int N) {
    __shared__ int s[SCAN_BLOCK];
    int t = threadIdx.x;
    int i = blockIdx.x * SCAN_BLOCK + t;
    int v = (i < N) ? deg[i] : 0;
    s[t] = v;
    __syncthreads();
    #pragma unroll
    for (int off = 1; off < SCAN_BLOCK; off <<= 1) {
        int u = (t >= off) ? s[t - off] : 0;
        __syncthreads();
        s[t] += u;
        __syncthreads();
    }
    int incl = s[t];
    int base = part[blockIdx.x];
    if (i < N) row_ptr[i] = base + incl - v;
    if (i == N - 1) row_ptr[N] = base + incl;
}

__global__ __launch_bounds__(256) void scatter_kernel(const int* __restrict__ src,
                                                      const int* __restrict__ dst,
                                                      int E, int N,
                                                      const int* __restrict__ row_ptr,
                                                      int* __restrict__ cursor,
                                                      int* __restrict__ col_src) {
    int e = blockIdx.x * 256 + threadIdx.x;
    int Etot = E + N;
    if (e >= Etot) return;
    int d, s;
    if (e < E) { d = dst[e]; s = src[e]; } else { d = e - E; s = e - E; }
    int pos = atomicAdd(&cursor[d], 1);
    col_src[row_ptr[d] + pos] = s;
}

// ---------------- GEMM: register-blocked 8x8 outer product ----------------
// Also emits packed-bf16 message buffer: Ybf[row][c] = (bf16 ch c, bf16 ch c+64), c in [0,64).
__global__ __launch_bounds__(128) void gemm_rb_kernel(const float* __restrict__ X,
                                                      const float* __restrict__ W,
                                                      float* __restrict__ Y,
                                                      unsigned* __restrict__ Ybf, int N) {
    __shared__ float Xs[BK][68];
    __shared__ float Wt[BK][128];
    const int t = threadIdx.x;
    const int r0 = blockIdx.x * 64;
    const int lane = t & 63, w = t >> 6;
    const int lx = lane & 15, ly = lane >> 4;
    const int row_base = w * 32 + ly * 8;      // tile-local row of acc[0]
    const int c1 = lx * 4, c2 = 64 + lx * 4;   // two col chunks

    float acc[8][8];
    #pragma unroll
    for (int i = 0; i < 8; ++i)
        #pragma unroll
        for (int j = 0; j < 8; ++j) acc[i][j] = 0.f;

    for (int kt = 0; kt < 128; kt += BK) {
        __syncthreads();
        #pragma unroll
        for (int i = 0; i < 4; ++i) {
            int idx = i * 128 + t;
            int row = idx >> 3, k4 = idx & 7;
            int gr = r0 + row;
            float4 g = make_float4(0.f, 0.f, 0.f, 0.f);
            if (gr < N) g = *(const float4*)(X + (size_t)gr * 128 + kt + k4 * 4);
            Xs[k4 * 4 + 0][row] = g.x;
            Xs[k4 * 4 + 1][row] = g.y;
            Xs[k4 * 4 + 2][row] = g.z;
            Xs[k4 * 4 + 3][row] = g.w;
        }
        #pragma unroll
        for (int i = 0; i < 8; ++i) {
            int idx = i * 128 + t;
            int wr = idx >> 5, c4 = idx & 31;
            *(float4*)&Wt[wr][c4 * 4] = *(const float4*)(W + (size_t)(kt + wr) * 128 + c4 * 4);
        }
        __syncthreads();

        #pragma unroll 8
        for (int k = 0; k < BK; ++k) {
            float4 a0 = *(const float4*)&Xs[k][row_base];
            float4 a1 = *(const float4*)&Xs[k][row_base + 4];
            float4 b0 = *(const float4*)&Wt[k][c1];
            float4 b1 = *(const float4*)&Wt[k][c2];
            float a[8] = {a0.x, a0.y, a0.z, a0.w, a1.x, a1.y, a1.z, a1.w};
            float b[8] = {b0.x, b0.y, b0.z, b0.w, b1.x, b1.y, b1.z, b1.w};
            #pragma unroll
            for (int i = 0; i < 8; ++i)
                #pragma unroll
                for (int j = 0; j < 8; ++j)
                    acc[i][j] = fmaf(a[i], b[j], acc[i][j]);
        }
    }

    #pragma unroll
    for (int i = 0; i < 8; ++i) {
        int gr = r0 + row_base + i;
        if (gr < N) {
            *(float4*)(Y + (size_t)gr * 128 + c1) =
                make_float4(acc[i][0], acc[i][1], acc[i][2], acc[i][3]);
            *(float4*)(Y + (size_t)gr * 128 + c2) =
                make_float4(acc[i][4], acc[i][5], acc[i][6], acc[i][7]);
            uint4 pk;
            pk.x = pack_bf16_pair(acc[i][0], acc[i][4]);
            pk.y = pack_bf16_pair(acc[i][1], acc[i][5]);
            pk.z = pack_bf16_pair(acc[i][2], acc[i][6]);
            pk.w = pack_bf16_pair(acc[i][3], acc[i][7]);
            *(uint4*)(Ybf + (size_t)gr * 64 + c1) = pk;
        }
    }
}

// ---------------- attention dots, layer 1 (H=8, C=16) ----------------
__global__ __launch_bounds__(256) void attdot1_kernel(const float* __restrict__ xh,
                                                      const float* __restrict__ attS,
                                                      const float* __restrict__ attD,
                                                      float* __restrict__ asrc,
                                                      float* __restrict__ adst, int N) {
    int node = blockIdx.x * 4 + (threadIdx.x >> 6);
    int lane = threadIdx.x & 63;
    if (node >= N) return;
    const float* row = xh + (size_t)node * 128;
    float x1 = row[lane], x2 = row[lane + 64];
    float s1 = x1 * attS[lane], s2 = x2 * attS[lane + 64];
    float d1 = x1 * attD[lane], d2 = x2 * attD[lane + 64];
    #pragma unroll
    for (int off = 8; off >= 1; off >>= 1) {
        s1 += __shfl_xor(s1, off, 64);
        s2 += __shfl_xor(s2, off, 64);
        d1 += __shfl_xor(d1, off, 64);
        d2 += __shfl_xor(d2, off, 64);
    }
    if ((lane & 15) == 0) {
        int h = lane >> 4;
        asrc[node * 8 + h]     = s1;
        asrc[node * 8 + h + 4] = s2;
        adst[node * 8 + h]     = d1;
        adst[node * 8 + h + 4] = d2;
    }
}

// ---------------- attention dots, layer 2 (H=1, C=128) ----------------
__global__ __launch_bounds__(256) void attdot2_kernel(const float* __restrict__ xh,
                                                      const float* __restrict__ attS,
                                                      const float* __restrict__ attD,
                                                      float* __restrict__ asrc,
                                                      float* __restrict__ adst, int N) {
    int node = blockIdx.x * 4 + (threadIdx.x >> 6);
    int lane = threadIdx.x & 63;
    if (node >= N) return;
    const float* row = xh + (size_t)node * 128;
    float x1 = row[lane], x2 = row[lane + 64];
    float ts = x1 * attS[lane] + x2 * attS[lane + 64];
    float td = x1 * attD[lane] + x2 * attD[lane + 64];
    #pragma unroll
    for (int off = 32; off >= 1; off >>= 1) {
        ts += __shfl_xor(ts, off, 64);
        td += __shfl_xor(td, off, 64);
    }
    if (lane == 0) { asrc[node] = ts; adst[node] = td; }
}

// ---------------- layer-1 aggregation: two-pass softmax + packed-bf16 gather ----------------
__global__ __launch_bounds__(256) void agg1_kernel(const unsigned* __restrict__ xhp,
                                                   const float* __restrict__ asrc,
                                                   const float* __restrict__ adst,
                                                   const int* __restrict__ row_ptr,
                                                   const int* __restrict__ col_src,
                                                   const float* __restrict__ b1,
                                                   float* __restrict__ out, int N) {
    int node = blockIdx.x * 4 + (threadIdx.x >> 6);
    int lane = threadIdx.x & 63;
    if (node >= N) return;
    int h1 = lane >> 4;                 // head of value v1=lane; v2=lane+64 -> head h1+4
    float ad1 = adst[node * 8 + h1];
    float ad2 = adst[node * 8 + h1 + 4];
    int beg = row_ptr[node], end = row_ptr[node + 1];

    // pass 1: exact max
    float m1 = -1e30f, m2 = -1e30f;
    for (int e = beg; e < end; ++e) {
        int sv = col_src[e];
        float e1 = asrc[sv * 8 + h1] + ad1;
        float e2 = asrc[sv * 8 + h1 + 4] + ad2;
        e1 = fmaxf(e1, NEG_SLOPE * e1);   // leaky relu
        e2 = fmaxf(e2, NEG_SLOPE * e2);
        m1 = fmaxf(m1, e1);
        m2 = fmaxf(m2, e2);
    }
    m1 *= LOG2E; m2 *= LOG2E;

    // pass 2: branch-free accumulate, one dword gather per edge
    float s1 = 0.f, s2 = 0.f, a1 = 0.f, a2 = 0.f;
    for (int e = beg; e < end; ++e) {
        int sv = col_src[e];
        float e1 = asrc[sv * 8 + h1] + ad1;
        float e2 = asrc[sv * 8 + h1 + 4] + ad2;
        e1 = fmaxf(e1, NEG_SLOPE * e1);
        e2 = fmaxf(e2, NEG_SLOPE * e2);
        float p1 = exp2f(fmaf(e1, LOG2E, -m1));
        float p2 = exp2f(fmaf(e2, LOG2E, -m2));
        unsigned v = xhp[(size_t)sv * 64 + lane];
        float x1 = __uint_as_float(v << 16);
        float x2 = __uint_as_float(v & 0xffff0000u);
        s1 += p1; a1 = fmaf(p1, x1, a1);
        s2 += p2; a2 = fmaf(p2, x2, a2);
    }
    float o1 = a1 / s1 + b1[lane];
    float o2 = a2 / s2 + b1[lane + 64];
    // ELU
    o1 = (o1 > 0.f) ? o1 : (__expf(o1) - 1.f);
    o2 = (o2 > 0.f) ? o2 : (__expf(o2) - 1.f);
    out[(size_t)node * 128 + lane]      = o1;
    out[(size_t)node * 128 + lane + 64] = o2;
}

// ---------------- layer-2 aggregation (H=1), two-pass + packed-bf16 gather ----------------
__global__ __launch_bounds__(256) void agg2_kernel(const unsigned* __restrict__ xhp,
                                                   const float* __restrict__ asrc,
                                                   const float* __restrict__ adst,
                                                   const int* __restrict__ row_ptr,
                                                   const int* __restrict__ col_src,
                                                   const float* __restrict__ b2,
                                                   float* __restrict__ out, int N) {
    int node = blockIdx.x * 4 + (threadIdx.x >> 6);
    int lane = threadIdx.x & 63;
    if (node >= N) return;
    float ad = adst[node];
    int beg = row_ptr[node], end = row_ptr[node + 1];

    float m = -1e30f;
    for (int e = beg; e < end; ++e) {
        float al = asrc[col_src[e]] + ad;
        al = fmaxf(al, NEG_SLOPE * al);
        m = fmaxf(m, al);
    }
    m *= LOG2E;

    float s = 0.f, a1 = 0.f, a2 = 0.f;
    for (int e = beg; e < end; ++e) {
        int sv = col_src[e];
        float al = asrc[sv] + ad;
        al = fmaxf(al, NEG_SLOPE * al);
        float p = exp2f(fmaf(al, LOG2E, -m));
        unsigned v = xhp[(size_t)sv * 64 + lane];
        float x1 = __uint_as_float(v << 16);
        float x2 = __uint_as_float(v & 0xffff0000u);
        s += p;
        a1 = fmaf(p, x1, a1);
        a2 = fmaf(p, x2, a2);
    }
    out[(size_t)node * 128 + lane]      = a1 / s + b2[lane];
    out[(size_t)node * 128 + lane + 64] = a2 / s + b2[lane + 64];
}

// ---------------- launch ----------------
extern "C" void kernel_launch(void* const* d_in, const int* in_sizes, int n_in,
                              void* d_out, int out_size, void* d_ws, size_t ws_size,
                              hipStream_t stream) {
    const float* x        = (const float*)d_in[0];
    const int*   src      = (const int*)d_in[1];
    const int*   dst      = (const int*)d_in[2];
    const float* W1       = (const float*)d_in[3];
    const float* att_src1 = (const float*)d_in[4];
    const float* att_dst1 = (const float*)d_in[5];
    const float* b1       = (const float*)d_in[6];
    const float* W2       = (const float*)d_in[7];
    const float* att_src2 = (const float*)d_in[8];
    const float* att_dst2 = (const float*)d_in[9];
    const float* b2       = (const float*)d_in[10];

    const int N = in_sizes[0] / 128;
    const int E = in_sizes[1];
    const int Etot = E + N;

    float* fws   = (float*)d_ws;
    float* xh    = fws;                    // N*128 (reused for both layers)
    float* asrc1 = xh + (size_t)N * 128;   // N*8
    float* adst1 = asrc1 + (size_t)N * 8;  // N*8
    float* asrc2 = adst1 + (size_t)N * 8;  // N
    float* adst2 = asrc2 + N;              // N
    int*   deg     = (int*)(adst2 + N);    // N
    int*   cursor  = deg + N;              // N
    int*   row_ptr = cursor + N;           // N+1
    int*   col_src = row_ptr + N + 1;      // Etot
    int*   part    = col_src + Etot;       // <=1024
    unsigned* xhp  = (unsigned*)(part + 1024);  // N*64 packed bf16 pairs

    float* h = (float*)d_out;              // layer-1 output lives in d_out

    const int nodeBlocks = (N + 3) / 4;
    const int edgeBlocks = (Etot + 255) / 256;
    const int gemmBlocks = (N + 63) / 64;
    const int scanBlocks = (N + SCAN_BLOCK - 1) / SCAN_BLOCK;   // 196 <= 1024

    // CSR build (shared by both layers)
    zero_int_kernel<<<(2 * N + 255) / 256, 256, 0, stream>>>(deg, 2 * N);
    count_deg_kernel<<<edgeBlocks, 256, 0, stream>>>(dst, E, N, deg);
    deg_partial_kernel<<<scanBlocks, SCAN_BLOCK, 0, stream>>>(deg, part, N);
    scan_part_kernel<<<1, 1024, 0, stream>>>(part, scanBlocks);
    scan_final_kernel<<<scanBlocks, SCAN_BLOCK, 0, stream>>>(deg, part, row_ptr, N);
    scatter_kernel<<<edgeBlocks, 256, 0, stream>>>(src, dst, E, N, row_ptr, cursor, col_src);

    // Layer 1
    gemm_rb_kernel<<<gemmBlocks, 128, 0, stream>>>(x, W1, xh, xhp, N);
    attdot1_kernel<<<nodeBlocks, 256, 0, stream>>>(xh, att_src1, att_dst1, asrc1, adst1, N);
    agg1_kernel<<<nodeBlocks, 256, 0, stream>>>(xhp, asrc1, adst1, row_ptr, col_src, b1, h, N);

    // Layer 2
    gemm_rb_kernel<<<gemmBlocks, 128, 0, stream>>>(h, W2, xh, xhp, N);
    attdot2_kernel<<<nodeBlocks, 256, 0, stream>>>(xh, att_src2, att_dst2, asrc2, adst2, N);
    agg2_kernel<<<nodeBlocks, 256, 0, stream>>>(xhp, asrc2, adst2, row_ptr, col_src, b2, (float*)d_out, N);
}

// Round 13
// 311.903 us; speedup vs baseline: 1.2977x; 1.2977x over previous
//
#include <hip/hip_runtime.h>
#include <hip/hip_bf16.h>
#include <math.h>

#define NEG_SLOPE 0.2f
#define SCAN_BLOCK 256
#define BK 32
#define LOG2E 1.4426950408889634f

__device__ __forceinline__ unsigned pack_bf16_pair(float lo, float hi) {
    unsigned ul = __float_as_uint(lo);
    ul += 0x7fffu + ((ul >> 16) & 1u);          // RNE
    unsigned uh = __float_as_uint(hi);
    uh += 0x7fffu + ((uh >> 16) & 1u);
    return (ul >> 16) | (uh & 0xffff0000u);
}

// ---------------- utility ----------------
__global__ __launch_bounds__(256) void zero_int_kernel(int* __restrict__ p, int n) {
    int i = blockIdx.x * 256 + threadIdx.x;
    if (i < n) p[i] = 0;
}

// ---------------- CSR build ----------------
__global__ __launch_bounds__(256) void count_deg_kernel(const int* __restrict__ dst,
                                                        int E, int N, int* __restrict__ deg) {
    int e = blockIdx.x * 256 + threadIdx.x;
    int Etot = E + N;
    if (e >= Etot) return;
    int d = (e < E) ? dst[e] : (e - E);
    atomicAdd(&deg[d], 1);
}

__global__ __launch_bounds__(SCAN_BLOCK) void deg_partial_kernel(const int* __restrict__ deg,
                                                                 int* __restrict__ part, int N) {
    __shared__ int red[SCAN_BLOCK];
    int t = threadIdx.x;
    int i = blockIdx.x * SCAN_BLOCK + t;
    red[t] = (i < N) ? deg[i] : 0;
    __syncthreads();
    #pragma unroll
    for (int off = SCAN_BLOCK / 2; off > 0; off >>= 1) {
        if (t < off) red[t] += red[t + off];
        __syncthreads();
    }
    if (t == 0) part[blockIdx.x] = red[0];
}

__global__ __launch_bounds__(1024) void scan_part_kernel(int* __restrict__ part, int nPart) {
    __shared__ int s[1024];
    int t = threadIdx.x;
    int v = (t < nPart) ? part[t] : 0;
    s[t] = v;
    __syncthreads();
    for (int off = 1; off < 1024; off <<= 1) {
        int u = (t >= off) ? s[t - off] : 0;
        __syncthreads();
        s[t] += u;
        __syncthreads();
    }
    if (t < nPart) part[t] = (t == 0) ? 0 : s[t - 1];   // exclusive block offsets
}

__global__ __launch_bounds__(SCAN_BLOCK) void scan_final_kernel(const int* __restrict__ deg,
                                                                const int* __restrict__ part,
                                                                int* __restrict__ row_ptr, int N) {
    __shared__ int s[SCAN_BLOCK];
    int t = threadIdx.x;
    int i = blockIdx.x * SCAN_BLOCK + t;
    int v = (i < N) ? deg[i] : 0;
    s[t] = v;
    __syncthreads();
    #pragma unroll
    for (int off = 1; off < SCAN_BLOCK; off <<= 1) {
        int u = (t >= off) ? s[t - off] : 0;
        __syncthreads();
        s[t] += u;
        __syncthreads();
    }
    int incl = s[t];
    int base = part[blockIdx.x];
    if (i < N) row_ptr[i] = base + incl - v;
    if (i == N - 1) row_ptr[N] = base + incl;
}

__global__ __launch_bounds__(256) void scatter_kernel(const int* __restrict__ src,
                                                      const int* __restrict__ dst,
                                                      int E, int N,
                                                      const int* __restrict__ row_ptr,
                                                      int* __restrict__ cursor,
                                                      int* __restrict__ col_src) {
    int e = blockIdx.x * 256 + threadIdx.x;
    int Etot = E + N;
    if (e >= Etot) return;
    int d, s;
    if (e < E) { d = dst[e]; s = src[e]; } else { d = e - E; s = e - E; }
    int pos = atomicAdd(&cursor[d], 1);
    col_src[row_ptr[d] + pos] = s;
}

// ---------------- GEMM: register-blocked 8x8 outer product ----------------
// Also emits packed-bf16 message buffer: Ybf[row][c] = (bf16 ch c, bf16 ch c+64), c in [0,64).
__global__ __launch_bounds__(128) void gemm_rb_kernel(const float* __restrict__ X,
                                                      const float* __restrict__ W,
                                                      float* __restrict__ Y,
                                                      unsigned* __restrict__ Ybf, int N) {
    __shared__ float Xs[BK][68];
    __shared__ float Wt[BK][128];
    const int t = threadIdx.x;
    const int r0 = blockIdx.x * 64;
    const int lane = t & 63, w = t >> 6;
    const int lx = lane & 15, ly = lane >> 4;
    const int row_base = w * 32 + ly * 8;      // tile-local row of acc[0]
    const int c1 = lx * 4, c2 = 64 + lx * 4;   // two col chunks

    float acc[8][8];
    #pragma unroll
    for (int i = 0; i < 8; ++i)
        #pragma unroll
        for (int j = 0; j < 8; ++j) acc[i][j] = 0.f;

    for (int kt = 0; kt < 128; kt += BK) {
        __syncthreads();
        #pragma unroll
        for (int i = 0; i < 4; ++i) {
            int idx = i * 128 + t;
            int row = idx >> 3, k4 = idx & 7;
            int gr = r0 + row;
            float4 g = make_float4(0.f, 0.f, 0.f, 0.f);
            if (gr < N) g = *(const float4*)(X + (size_t)gr * 128 + kt + k4 * 4);
            Xs[k4 * 4 + 0][row] = g.x;
            Xs[k4 * 4 + 1][row] = g.y;
            Xs[k4 * 4 + 2][row] = g.z;
            Xs[k4 * 4 + 3][row] = g.w;
        }
        #pragma unroll
        for (int i = 0; i < 8; ++i) {
            int idx = i * 128 + t;
            int wr = idx >> 5, c4 = idx & 31;
            *(float4*)&Wt[wr][c4 * 4] = *(const float4*)(W + (size_t)(kt + wr) * 128 + c4 * 4);
        }
        __syncthreads();

        #pragma unroll 8
        for (int k = 0; k < BK; ++k) {
            float4 a0 = *(const float4*)&Xs[k][row_base];
            float4 a1 = *(const float4*)&Xs[k][row_base + 4];
            float4 b0 = *(const float4*)&Wt[k][c1];
            float4 b1 = *(const float4*)&Wt[k][c2];
            float a[8] = {a0.x, a0.y, a0.z, a0.w, a1.x, a1.y, a1.z, a1.w};
            float b[8] = {b0.x, b0.y, b0.z, b0.w, b1.x, b1.y, b1.z, b1.w};
            #pragma unroll
            for (int i = 0; i < 8; ++i)
                #pragma unroll
                for (int j = 0; j < 8; ++j)
                    acc[i][j] = fmaf(a[i], b[j], acc[i][j]);
        }
    }

    #pragma unroll
    for (int i = 0; i < 8; ++i) {
        int gr = r0 + row_base + i;
        if (gr < N) {
            *(float4*)(Y + (size_t)gr * 128 + c1) =
                make_float4(acc[i][0], acc[i][1], acc[i][2], acc[i][3]);
            *(float4*)(Y + (size_t)gr * 128 + c2) =
                make_float4(acc[i][4], acc[i][5], acc[i][6], acc[i][7]);
            uint4 pk;
            pk.x = pack_bf16_pair(acc[i][0], acc[i][4]);
            pk.y = pack_bf16_pair(acc[i][1], acc[i][5]);
            pk.z = pack_bf16_pair(acc[i][2], acc[i][6]);
            pk.w = pack_bf16_pair(acc[i][3], acc[i][7]);
            *(uint4*)(Ybf + (size_t)gr * 64 + c1) = pk;
        }
    }
}

// ---------------- attention dots, layer 1 (H=8, C=16) ----------------
__global__ __launch_bounds__(256) void attdot1_kernel(const float* __restrict__ xh,
                                                      const float* __restrict__ attS,
                                                      const float* __restrict__ attD,
                                                      float* __restrict__ asrc,
                                                      float* __restrict__ adst, int N) {
    int node = blockIdx.x * 4 + (threadIdx.x >> 6);
    int lane = threadIdx.x & 63;
    if (node >= N) return;
    const float* row = xh + (size_t)node * 128;
    float x1 = row[lane], x2 = row[lane + 64];
    float s1 = x1 * attS[lane], s2 = x2 * attS[lane + 64];
    float d1 = x1 * attD[lane], d2 = x2 * attD[lane + 64];
    #pragma unroll
    for (int off = 8; off >= 1; off >>= 1) {
        s1 += __shfl_xor(s1, off, 64);
        s2 += __shfl_xor(s2, off, 64);
        d1 += __shfl_xor(d1, off, 64);
        d2 += __shfl_xor(d2, off, 64);
    }
    if ((lane & 15) == 0) {
        int h = lane >> 4;
        asrc[node * 8 + h]     = s1;
        asrc[node * 8 + h + 4] = s2;
        adst[node * 8 + h]     = d1;
        adst[node * 8 + h + 4] = d2;
    }
}

// ---------------- attention dots, layer 2 (H=1, C=128) ----------------
__global__ __launch_bounds__(256) void attdot2_kernel(const float* __restrict__ xh,
                                                      const float* __restrict__ attS,
                                                      const float* __restrict__ attD,
                                                      float* __restrict__ asrc,
                                                      float* __restrict__ adst, int N) {
    int node = blockIdx.x * 4 + (threadIdx.x >> 6);
    int lane = threadIdx.x & 63;
    if (node >= N) return;
    const float* row = xh + (size_t)node * 128;
    float x1 = row[lane], x2 = row[lane + 64];
    float ts = x1 * attS[lane] + x2 * attS[lane + 64];
    float td = x1 * attD[lane] + x2 * attD[lane + 64];
    #pragma unroll
    for (int off = 32; off >= 1; off >>= 1) {
        ts += __shfl_xor(ts, off, 64);
        td += __shfl_xor(td, off, 64);
    }
    if (lane == 0) { asrc[node] = ts; adst[node] = td; }
}

// ---------------- layer-1 aggregation: lane-parallel alphas + shfl-broadcast gather ----------
// 16 lanes per head-group each own one edge; alpha/max computed with 16-way MLP;
// gather loop gets sv/p via shfl (no dependent load) -> unroll-4 independent gathers.
__global__ __launch_bounds__(256) void agg1_kernel(const unsigned* __restrict__ xhp,
                                                   const float* __restrict__ asrc,
                                                   const float* __restrict__ adst,
                                                   const int* __restrict__ row_ptr,
                                                   const int* __restrict__ col_src,
                                                   const float* __restrict__ b1,
                                                   float* __restrict__ out, int N) {
    int node = blockIdx.x * 4 + (threadIdx.x >> 6);
    int lane = threadIdx.x & 63;
    if (node >= N) return;
    const int grp = lane >> 4;        // head pair (grp, grp+4)
    const int lx = lane & 15;
    const int gbase = lane & 48;
    float ad1 = adst[node * 8 + grp];
    float ad2 = adst[node * 8 + grp + 4];
    int beg = row_ptr[node], end = row_ptr[node + 1];
    int deg = end - beg;

    float s1 = 0.f, s2 = 0.f, acc1 = 0.f, acc2 = 0.f;

    if (deg <= 16) {                 // fast path (~98% of nodes)
        bool valid = lx < deg;
        int sv = col_src[valid ? (beg + lx) : beg];
        float al1 = asrc[sv * 8 + grp] + ad1;
        float al2 = asrc[sv * 8 + grp + 4] + ad2;
        al1 = fmaxf(al1, NEG_SLOPE * al1);
        al2 = fmaxf(al2, NEG_SLOPE * al2);
        float m1 = valid ? al1 : -1e30f;
        float m2 = valid ? al2 : -1e30f;
        #pragma unroll
        for (int off = 1; off < 16; off <<= 1) {
            m1 = fmaxf(m1, __shfl_xor(m1, off, 64));
            m2 = fmaxf(m2, __shfl_xor(m2, off, 64));
        }
        float p1 = valid ? exp2f((al1 - m1) * LOG2E) : 0.f;
        float p2 = valid ? exp2f((al2 - m2) * LOG2E) : 0.f;
        #pragma unroll 4
        for (int i = 0; i < deg; ++i) {
            int   svi = __shfl(sv, gbase + i, 64);
            float q1  = __shfl(p1, gbase + i, 64);
            float q2  = __shfl(p2, gbase + i, 64);
            unsigned v = xhp[(size_t)svi * 64 + lane];
            float x1 = __uint_as_float(v << 16);
            float x2 = __uint_as_float(v & 0xffff0000u);
            s1 += q1; acc1 = fmaf(q1, x1, acc1);
            s2 += q2; acc2 = fmaf(q2, x2, acc2);
        }
    } else {                          // general chunked path
        float m1 = -1e30f, m2 = -1e30f;
        for (int c = beg; c < end; c += 16) {
            int e = c + lx;
            bool valid = e < end;
            int sv = col_src[valid ? e : beg];
            float al1 = asrc[sv * 8 + grp] + ad1;
            float al2 = asrc[sv * 8 + grp + 4] + ad2;
            al1 = fmaxf(al1, NEG_SLOPE * al1);
            al2 = fmaxf(al2, NEG_SLOPE * al2);
            if (valid) { m1 = fmaxf(m1, al1); m2 = fmaxf(m2, al2); }
        }
        #pragma unroll
        for (int off = 1; off < 16; off <<= 1) {
            m1 = fmaxf(m1, __shfl_xor(m1, off, 64));
            m2 = fmaxf(m2, __shfl_xor(m2, off, 64));
        }
        for (int c = beg; c < end; c += 16) {
            int e = c + lx;
            bool valid = e < end;
            int sv = col_src[valid ? e : beg];
            float al1 = asrc[sv * 8 + grp] + ad1;
            float al2 = asrc[sv * 8 + grp + 4] + ad2;
            al1 = fmaxf(al1, NEG_SLOPE * al1);
            al2 = fmaxf(al2, NEG_SLOPE * al2);
            float p1 = valid ? exp2f((al1 - m1) * LOG2E) : 0.f;
            float p2 = valid ? exp2f((al2 - m2) * LOG2E) : 0.f;
            int cnt = min(16, end - c);
            #pragma unroll 4
            for (int i = 0; i < cnt; ++i) {
                int   svi = __shfl(sv, gbase + i, 64);
                float q1  = __shfl(p1, gbase + i, 64);
                float q2  = __shfl(p2, gbase + i, 64);
                unsigned v = xhp[(size_t)svi * 64 + lane];
                float x1 = __uint_as_float(v << 16);
                float x2 = __uint_as_float(v & 0xffff0000u);
                s1 += q1; acc1 = fmaf(q1, x1, acc1);
                s2 += q2; acc2 = fmaf(q2, x2, acc2);
            }
        }
    }

    float o1 = acc1 / s1 + b1[lane];
    float o2 = acc2 / s2 + b1[lane + 64];
    // ELU
    o1 = (o1 > 0.f) ? o1 : (__expf(o1) - 1.f);
    o2 = (o2 > 0.f) ? o2 : (__expf(o2) - 1.f);
    out[(size_t)node * 128 + lane]      = o1;
    out[(size_t)node * 128 + lane + 64] = o2;
}

// ---------------- layer-2 aggregation (H=1): 64-lane-parallel alphas ----------------
__global__ __launch_bounds__(256) void agg2_kernel(const unsigned* __restrict__ xhp,
                                                   const float* __restrict__ asrc,
                                                   const float* __restrict__ adst,
                                                   const int* __restrict__ row_ptr,
                                                   const int* __restrict__ col_src,
                                                   const float* __restrict__ b2,
                                                   float* __restrict__ out, int N) {
    int node = blockIdx.x * 4 + (threadIdx.x >> 6);
    int lane = threadIdx.x & 63;
    if (node >= N) return;
    float ad = adst[node];
    int beg = row_ptr[node], end = row_ptr[node + 1];
    int deg = end - beg;

    float s = 0.f, acc1 = 0.f, acc2 = 0.f;

    if (deg <= 64) {                 // fast path (~100% of nodes)
        bool valid = lane < deg;
        int sv = col_src[valid ? (beg + lane) : beg];
        float al = asrc[sv] + ad;
        al = fmaxf(al, NEG_SLOPE * al);
        float m = valid ? al : -1e30f;
        #pragma unroll
        for (int off = 1; off < 64; off <<= 1)
            m = fmaxf(m, __shfl_xor(m, off, 64));
        float p = valid ? exp2f((al - m) * LOG2E) : 0.f;
        #pragma unroll 4
        for (int i = 0; i < deg; ++i) {
            int   svi = __shfl(sv, i, 64);
            float q   = __shfl(p, i, 64);
            unsigned v = xhp[(size_t)svi * 64 + lane];
            float x1 = __uint_as_float(v << 16);
            float x2 = __uint_as_float(v & 0xffff0000u);
            s += q;
            acc1 = fmaf(q, x1, acc1);
            acc2 = fmaf(q, x2, acc2);
        }
    } else {
        float m = -1e30f;
        for (int c = beg; c < end; c += 64) {
            int e = c + lane;
            bool valid = e < end;
            int sv = col_src[valid ? e : beg];
            float al = asrc[sv] + ad;
            al = fmaxf(al, NEG_SLOPE * al);
            if (valid) m = fmaxf(m, al);
        }
        #pragma unroll
        for (int off = 1; off < 64; off <<= 1)
            m = fmaxf(m, __shfl_xor(m, off, 64));
        for (int c = beg; c < end; c += 64) {
            int e = c + lane;
            bool valid = e < end;
            int sv = col_src[valid ? e : beg];
            float al = asrc[sv] + ad;
            al = fmaxf(al, NEG_SLOPE * al);
            float p = valid ? exp2f((al - m) * LOG2E) : 0.f;
            int cnt = min(64, end - c);
            #pragma unroll 4
            for (int i = 0; i < cnt; ++i) {
                int   svi = __shfl(sv, i, 64);
                float q   = __shfl(p, i, 64);
                unsigned v = xhp[(size_t)svi * 64 + lane];
                float x1 = __uint_as_float(v << 16);
                float x2 = __uint_as_float(v & 0xffff0000u);
                s += q;
                acc1 = fmaf(q, x1, acc1);
                acc2 = fmaf(q, x2, acc2);
            }
        }
    }

    out[(size_t)node * 128 + lane]      = acc1 / s + b2[lane];
    out[(size_t)node * 128 + lane + 64] = acc2 / s + b2[lane + 64];
}

// ---------------- launch ----------------
extern "C" void kernel_launch(void* const* d_in, const int* in_sizes, int n_in,
                              void* d_out, int out_size, void* d_ws, size_t ws_size,
                              hipStream_t stream) {
    const float* x        = (const float*)d_in[0];
    const int*   src      = (const int*)d_in[1];
    const int*   dst      = (const int*)d_in[2];
    const float* W1       = (const float*)d_in[3];
    const float* att_src1 = (const float*)d_in[4];
    const float* att_dst1 = (const float*)d_in[5];
    const float* b1       = (const float*)d_in[6];
    const float* W2       = (const float*)d_in[7];
    const float* att_src2 = (const float*)d_in[8];
    const float* att_dst2 = (const float*)d_in[9];
    const float* b2       = (const float*)d_in[10];

    const int N = in_sizes[0] / 128;
    const int E = in_sizes[1];
    const int Etot = E + N;

    float* fws   = (float*)d_ws;
    float* xh    = fws;                    // N*128 (reused for both layers)
    float* asrc1 = xh + (size_t)N * 128;   // N*8
    float* adst1 = asrc1 + (size_t)N * 8;  // N*8
    float* asrc2 = adst1 + (size_t)N * 8;  // N
    float* adst2 = asrc2 + N;              // N
    int*   deg     = (int*)(adst2 + N);    // N
    int*   cursor  = deg + N;              // N
    int*   row_ptr = cursor + N;           // N+1
    int*   col_src = row_ptr + N + 1;      // Etot
    int*   part    = col_src + Etot;       // <=1024
    unsigned* xhp  = (unsigned*)(part + 1024);  // N*64 packed bf16 pairs

    float* h = (float*)d_out;              // layer-1 output lives in d_out

    const int nodeBlocks = (N + 3) / 4;
    const int edgeBlocks = (Etot + 255) / 256;
    const int gemmBlocks = (N + 63) / 64;
    const int scanBlocks = (N + SCAN_BLOCK - 1) / SCAN_BLOCK;   // 196 <= 1024

    // CSR build (shared by both layers)
    zero_int_kernel<<<(2 * N + 255) / 256, 256, 0, stream>>>(deg, 2 * N);
    count_deg_kernel<<<edgeBlocks, 256, 0, stream>>>(dst, E, N, deg);
    deg_partial_kernel<<<scanBlocks, SCAN_BLOCK, 0, stream>>>(deg, part, N);
    scan_part_kernel<<<1, 1024, 0, stream>>>(part, scanBlocks);
    scan_final_kernel<<<scanBlocks, SCAN_BLOCK, 0, stream>>>(deg, part, row_ptr, N);
    scatter_kernel<<<edgeBlocks, 256, 0, stream>>>(src, dst, E, N, row_ptr, cursor, col_src);

    // Layer 1
    gemm_rb_kernel<<<gemmBlocks, 128, 0, stream>>>(x, W1, xh, xhp, N);
    attdot1_kernel<<<nodeBlocks, 256, 0, stream>>>(xh, att_src1, att_dst1, asrc1, adst1, N);
    agg1_kernel<<<nodeBlocks, 256, 0, stream>>>(xhp, asrc1, adst1, row_ptr, col_src, b1, h, N);

    // Layer 2
    gemm_rb_kernel<<<gemmBlocks, 128, 0, stream>>>(h, W2, xh, xhp, N);
    attdot2_kernel<<<nodeBlocks, 256, 0, stream>>>(xh, att_src2, att_dst2, asrc2, adst2, N);
    agg2_kernel<<<nodeBlocks, 256, 0, stream>>>(xhp, asrc2, adst2, row_ptr, col_src, b2, (float*)d_out, N);
}

// Round 15
// 282.124 us; speedup vs baseline: 1.4347x; 1.1056x over previous
//
#include <hip/hip_runtime.h>
#include <hip/hip_bf16.h>
#include <math.h>

#define NEG_SLOPE 0.2f
#define SCAN_BLOCK 256
#define BK 32
#define LOG2E 1.4426950408889634f

__device__ __forceinline__ unsigned pack_bf16_pair(float lo, float hi) {
    unsigned ul = __float_as_uint(lo);
    ul += 0x7fffu + ((ul >> 16) & 1u);          // RNE
    unsigned uh = __float_as_uint(hi);
    uh += 0x7fffu + ((uh >> 16) & 1u);
    return (ul >> 16) | (uh & 0xffff0000u);
}

// ---------------- utility ----------------
__global__ __launch_bounds__(256) void zero_int_kernel(int* __restrict__ p, int n) {
    int i = blockIdx.x * 256 + threadIdx.x;
    if (i < n) p[i] = 0;
}

// ---------------- CSR build ----------------
__global__ __launch_bounds__(256) void count_deg_kernel(const int* __restrict__ dst,
                                                        int E, int N, int* __restrict__ deg) {
    int e = blockIdx.x * 256 + threadIdx.x;
    int Etot = E + N;
    if (e >= Etot) return;
    int d = (e < E) ? dst[e] : (e - E);
    atomicAdd(&deg[d], 1);
}

__global__ __launch_bounds__(SCAN_BLOCK) void deg_partial_kernel(const int* __restrict__ deg,
                                                                 int* __restrict__ part, int N) {
    __shared__ int red[SCAN_BLOCK];
    int t = threadIdx.x;
    int i = blockIdx.x * SCAN_BLOCK + t;
    red[t] = (i < N) ? deg[i] : 0;
    __syncthreads();
    #pragma unroll
    for (int off = SCAN_BLOCK / 2; off > 0; off >>= 1) {
        if (t < off) red[t] += red[t + off];
        __syncthreads();
    }
    if (t == 0) part[blockIdx.x] = red[0];
}

__global__ __launch_bounds__(1024) void scan_part_kernel(int* __restrict__ part, int nPart) {
    __shared__ int s[1024];
    int t = threadIdx.x;
    int v = (t < nPart) ? part[t] : 0;
    s[t] = v;
    __syncthreads();
    for (int off = 1; off < 1024; off <<= 1) {
        int u = (t >= off) ? s[t - off] : 0;
        __syncthreads();
        s[t] += u;
        __syncthreads();
    }
    if (t < nPart) part[t] = (t == 0) ? 0 : s[t - 1];   // exclusive block offsets
}

__global__ __launch_bounds__(SCAN_BLOCK) void scan_final_kernel(const int* __restrict__ deg,
                                                                const int* __restrict__ part,
                                                                int* __restrict__ row_ptr, int N) {
    __shared__ int s[SCAN_BLOCK];
    int t = threadIdx.x;
    int i = blockIdx.x * SCAN_BLOCK + t;
    int v = (i < N) ? deg[i] : 0;
    s[t] = v;
    __syncthreads();
    #pragma unroll
    for (int off = 1; off < SCAN_BLOCK; off <<= 1) {
        int u = (t >= off) ? s[t - off] : 0;
        __syncthreads();
        s[t] += u;
        __syncthreads();
    }
    int incl = s[t];
    int base = part[blockIdx.x];
    if (i < N) row_ptr[i] = base + incl - v;
    if (i == N - 1) row_ptr[N] = base + incl;
}

__global__ __launch_bounds__(256) void scatter_kernel(const int* __restrict__ src,
                                                      const int* __restrict__ dst,
                                                      int E, int N,
                                                      const int* __restrict__ row_ptr,
                                                      int* __restrict__ cursor,
                                                      int* __restrict__ col_src) {
    int e = blockIdx.x * 256 + threadIdx.x;
    int Etot = E + N;
    if (e >= Etot) return;
    int d, s;
    if (e < E) { d = dst[e]; s = src[e]; } else { d = e - E; s = e - E; }
    int pos = atomicAdd(&cursor[d], 1);
    col_src[row_ptr[d] + pos] = s;
}

// ---------------- GEMM fused: 256 thr, 4 rows x 8 cols/thread, attdot in epilogue ----------
// Writes ONLY packed-bf16 Ybf + asrc/adst (no fp32 Y).
// heads==8: thread's col chunks c1 (head lx>>2) and c2 (head (lx>>2)+4); reduce over lx&3.
// heads==1: reduce over all 16 lx.
__global__ __launch_bounds__(256) void gemm_fused_kernel(const float* __restrict__ X,
                                                         const float* __restrict__ W,
                                                         const float* __restrict__ attS,
                                                         const float* __restrict__ attD,
                                                         unsigned* __restrict__ Ybf,
                                                         float* __restrict__ asrc,
                                                         float* __restrict__ adst,
                                                         int N, int heads) {
    __shared__ float Xs[BK][68];
    __shared__ float Wt[BK][128];
    __shared__ float attSs[128], attDs[128];
    const int t = threadIdx.x;
    const int r0 = blockIdx.x * 64;
    const int lane = t & 63, wv = t >> 6;
    const int lx = lane & 15, ly = lane >> 4;
    const int row_base = wv * 16 + ly * 4;     // tile-local row of acc[0]
    const int c1 = lx * 4, c2 = 64 + lx * 4;   // two col chunks

    if (t < 128) { attSs[t] = attS[t]; attDs[t] = attD[t]; }

    float acc[4][8];
    #pragma unroll
    for (int i = 0; i < 4; ++i)
        #pragma unroll
        for (int j = 0; j < 8; ++j) acc[i][j] = 0.f;

    for (int kt = 0; kt < 128; kt += BK) {
        __syncthreads();
        // stage X tile (64 rows x BK) transposed: 512 float4s, 2 per thread
        #pragma unroll
        for (int i = 0; i < 2; ++i) {
            int idx = i * 256 + t;
            int row = idx >> 3, k4 = idx & 7;
            int gr = r0 + row;
            float4 g = make_float4(0.f, 0.f, 0.f, 0.f);
            if (gr < N) g = *(const float4*)(X + (size_t)gr * 128 + kt + k4 * 4);
            Xs[k4 * 4 + 0][row] = g.x;
            Xs[k4 * 4 + 1][row] = g.y;
            Xs[k4 * 4 + 2][row] = g.z;
            Xs[k4 * 4 + 3][row] = g.w;
        }
        // stage W tile (BK x 128): 1024 float4s, 4 per thread
        #pragma unroll
        for (int i = 0; i < 4; ++i) {
            int idx = i * 256 + t;
            int wr = idx >> 5, c4 = idx & 31;
            *(float4*)&Wt[wr][c4 * 4] = *(const float4*)(W + (size_t)(kt + wr) * 128 + c4 * 4);
        }
        __syncthreads();

        #pragma unroll 8
        for (int k = 0; k < BK; ++k) {
            float4 a0 = *(const float4*)&Xs[k][row_base];
            float4 b0 = *(const float4*)&Wt[k][c1];
            float4 b1 = *(const float4*)&Wt[k][c2];
            float a[4] = {a0.x, a0.y, a0.z, a0.w};
            float b[8] = {b0.x, b0.y, b0.z, b0.w, b1.x, b1.y, b1.z, b1.w};
            #pragma unroll
            for (int i = 0; i < 4; ++i)
                #pragma unroll
                for (int j = 0; j < 8; ++j)
                    acc[i][j] = fmaf(a[i], b[j], acc[i][j]);
        }
    }

    #pragma unroll
    for (int i = 0; i < 4; ++i) {
        int gr = r0 + row_base + i;
        bool ok = gr < N;
        // packed-bf16 message write
        if (ok) {
            uint4 pk;
            pk.x = pack_bf16_pair(acc[i][0], acc[i][4]);
            pk.y = pack_bf16_pair(acc[i][1], acc[i][5]);
            pk.z = pack_bf16_pair(acc[i][2], acc[i][6]);
            pk.w = pack_bf16_pair(acc[i][3], acc[i][7]);
            *(uint4*)(Ybf + (size_t)gr * 64 + c1) = pk;
        }
        // fused attention dots
        if (heads == 8) {
            float s0 = 0.f, s1 = 0.f, d0 = 0.f, d1 = 0.f;
            #pragma unroll
            for (int j = 0; j < 4; ++j) {
                s0 = fmaf(acc[i][j],     attSs[c1 + j], s0);
                d0 = fmaf(acc[i][j],     attDs[c1 + j], d0);
                s1 = fmaf(acc[i][4 + j], attSs[c2 + j], s1);
                d1 = fmaf(acc[i][4 + j], attDs[c2 + j], d1);
            }
            s0 += __shfl_xor(s0, 1, 64); s0 += __shfl_xor(s0, 2, 64);
            s1 += __shfl_xor(s1, 1, 64); s1 += __shfl_xor(s1, 2, 64);
            d0 += __shfl_xor(d0, 1, 64); d0 += __shfl_xor(d0, 2, 64);
            d1 += __shfl_xor(d1, 1, 64); d1 += __shfl_xor(d1, 2, 64);
            if (ok && (lx & 3) == 0) {
                int hA = lx >> 2;
                asrc[gr * 8 + hA]     = s0;
                asrc[gr * 8 + hA + 4] = s1;
                adst[gr * 8 + hA]     = d0;
                adst[gr * 8 + hA + 4] = d1;
            }
        } else {
            float sp = 0.f, dp = 0.f;
            #pragma unroll
            for (int j = 0; j < 4; ++j) {
                sp = fmaf(acc[i][j],     attSs[c1 + j], sp);
                sp = fmaf(acc[i][4 + j], attSs[c2 + j], sp);
                dp = fmaf(acc[i][j],     attDs[c1 + j], dp);
                dp = fmaf(acc[i][4 + j], attDs[c2 + j], dp);
            }
            #pragma unroll
            for (int off = 1; off < 16; off <<= 1) {
                sp += __shfl_xor(sp, off, 64);
                dp += __shfl_xor(dp, off, 64);
            }
            if (ok && lx == 0) { asrc[gr] = sp; adst[gr] = dp; }
        }
    }
}

// ---------------- layer-1 aggregation: lane-parallel alphas + shfl-broadcast gather ----------
__global__ __launch_bounds__(256) void agg1_kernel(const unsigned* __restrict__ xhp,
                                                   const float* __restrict__ asrc,
                                                   const float* __restrict__ adst,
                                                   const int* __restrict__ row_ptr,
                                                   const int* __restrict__ col_src,
                                                   const float* __restrict__ b1,
                                                   float* __restrict__ out, int N) {
    int node = blockIdx.x * 4 + (threadIdx.x >> 6);
    int lane = threadIdx.x & 63;
    if (node >= N) return;
    const int grp = lane >> 4;        // head pair (grp, grp+4)
    const int lx = lane & 15;
    const int gbase = lane & 48;
    float ad1 = adst[node * 8 + grp];
    float ad2 = adst[node * 8 + grp + 4];
    int beg = row_ptr[node], end = row_ptr[node + 1];
    int deg = end - beg;

    float s1 = 0.f, s2 = 0.f, acc1 = 0.f, acc2 = 0.f;

    if (deg <= 16) {                 // fast path (~98% of nodes)
        bool valid = lx < deg;
        int sv = col_src[valid ? (beg + lx) : beg];
        float al1 = asrc[sv * 8 + grp] + ad1;
        float al2 = asrc[sv * 8 + grp + 4] + ad2;
        al1 = fmaxf(al1, NEG_SLOPE * al1);
        al2 = fmaxf(al2, NEG_SLOPE * al2);
        float m1 = valid ? al1 : -1e30f;
        float m2 = valid ? al2 : -1e30f;
        #pragma unroll
        for (int off = 1; off < 16; off <<= 1) {
            m1 = fmaxf(m1, __shfl_xor(m1, off, 64));
            m2 = fmaxf(m2, __shfl_xor(m2, off, 64));
        }
        float p1 = valid ? exp2f((al1 - m1) * LOG2E) : 0.f;
        float p2 = valid ? exp2f((al2 - m2) * LOG2E) : 0.f;
        #pragma unroll 4
        for (int i = 0; i < deg; ++i) {
            int   svi = __shfl(sv, gbase + i, 64);
            float q1  = __shfl(p1, gbase + i, 64);
            float q2  = __shfl(p2, gbase + i, 64);
            unsigned v = xhp[(size_t)svi * 64 + lane];
            float x1 = __uint_as_float(v << 16);
            float x2 = __uint_as_float(v & 0xffff0000u);
            s1 += q1; acc1 = fmaf(q1, x1, acc1);
            s2 += q2; acc2 = fmaf(q2, x2, acc2);
        }
    } else {                          // general chunked path
        float m1 = -1e30f, m2 = -1e30f;
        for (int c = beg; c < end; c += 16) {
            int e = c + lx;
            bool valid = e < end;
            int sv = col_src[valid ? e : beg];
            float al1 = asrc[sv * 8 + grp] + ad1;
            float al2 = asrc[sv * 8 + grp + 4] + ad2;
            al1 = fmaxf(al1, NEG_SLOPE * al1);
            al2 = fmaxf(al2, NEG_SLOPE * al2);
            if (valid) { m1 = fmaxf(m1, al1); m2 = fmaxf(m2, al2); }
        }
        #pragma unroll
        for (int off = 1; off < 16; off <<= 1) {
            m1 = fmaxf(m1, __shfl_xor(m1, off, 64));
            m2 = fmaxf(m2, __shfl_xor(m2, off, 64));
        }
        for (int c = beg; c < end; c += 16) {
            int e = c + lx;
            bool valid = e < end;
            int sv = col_src[valid ? e : beg];
            float al1 = asrc[sv * 8 + grp] + ad1;
            float al2 = asrc[sv * 8 + grp + 4] + ad2;
            al1 = fmaxf(al1, NEG_SLOPE * al1);
            al2 = fmaxf(al2, NEG_SLOPE * al2);
            float p1 = valid ? exp2f((al1 - m1) * LOG2E) : 0.f;
            float p2 = valid ? exp2f((al2 - m2) * LOG2E) : 0.f;
            int cnt = min(16, end - c);
            #pragma unroll 4
            for (int i = 0; i < cnt; ++i) {
                int   svi = __shfl(sv, gbase + i, 64);
                float q1  = __shfl(p1, gbase + i, 64);
                float q2  = __shfl(p2, gbase + i, 64);
                unsigned v = xhp[(size_t)svi * 64 + lane];
                float x1 = __uint_as_float(v << 16);
                float x2 = __uint_as_float(v & 0xffff0000u);
                s1 += q1; acc1 = fmaf(q1, x1, acc1);
                s2 += q2; acc2 = fmaf(q2, x2, acc2);
            }
        }
    }

    float o1 = acc1 / s1 + b1[lane];
    float o2 = acc2 / s2 + b1[lane + 64];
    // ELU
    o1 = (o1 > 0.f) ? o1 : (__expf(o1) - 1.f);
    o2 = (o2 > 0.f) ? o2 : (__expf(o2) - 1.f);
    out[(size_t)node * 128 + lane]      = o1;
    out[(size_t)node * 128 + lane + 64] = o2;
}

// ---------------- layer-2 aggregation (H=1): 64-lane-parallel alphas ----------------
__global__ __launch_bounds__(256) void agg2_kernel(const unsigned* __restrict__ xhp,
                                                   const float* __restrict__ asrc,
                                                   const float* __restrict__ adst,
                                                   const int* __restrict__ row_ptr,
                                                   const int* __restrict__ col_src,
                                                   const float* __restrict__ b2,
                                                   float* __restrict__ out, int N) {
    int node = blockIdx.x * 4 + (threadIdx.x >> 6);
    int lane = threadIdx.x & 63;
    if (node >= N) return;
    float ad = adst[node];
    int beg = row_ptr[node], end = row_ptr[node + 1];
    int deg = end - beg;

    float s = 0.f, acc1 = 0.f, acc2 = 0.f;

    if (deg <= 64) {                 // fast path (~100% of nodes)
        bool valid = lane < deg;
        int sv = col_src[valid ? (beg + lane) : beg];
        float al = asrc[sv] + ad;
        al = fmaxf(al, NEG_SLOPE * al);
        float m = valid ? al : -1e30f;
        #pragma unroll
        for (int off = 1; off < 64; off <<= 1)
            m = fmaxf(m, __shfl_xor(m, off, 64));
        float p = valid ? exp2f((al - m) * LOG2E) : 0.f;
        #pragma unroll 4
        for (int i = 0; i < deg; ++i) {
            int   svi = __shfl(sv, i, 64);
            float q   = __shfl(p, i, 64);
            unsigned v = xhp[(size_t)svi * 64 + lane];
            float x1 = __uint_as_float(v << 16);
            float x2 = __uint_as_float(v & 0xffff0000u);
            s += q;
            acc1 = fmaf(q, x1, acc1);
            acc2 = fmaf(q, x2, acc2);
        }
    } else {
        float m = -1e30f;
        for (int c = beg; c < end; c += 64) {
            int e = c + lane;
            bool valid = e < end;
            int sv = col_src[valid ? e : beg];
            float al = asrc[sv] + ad;
            al = fmaxf(al, NEG_SLOPE * al);
            if (valid) m = fmaxf(m, al);
        }
        #pragma unroll
        for (int off = 1; off < 64; off <<= 1)
            m = fmaxf(m, __shfl_xor(m, off, 64));
        for (int c = beg; c < end; c += 64) {
            int e = c + lane;
            bool valid = e < end;
            int sv = col_src[valid ? e : beg];
            float al = asrc[sv] + ad;
            al = fmaxf(al, NEG_SLOPE * al);
            float p = valid ? exp2f((al - m) * LOG2E) : 0.f;
            int cnt = min(64, end - c);
            #pragma unroll 4
            for (int i = 0; i < cnt; ++i) {
                int   svi = __shfl(sv, i, 64);
                float q   = __shfl(p, i, 64);
                unsigned v = xhp[(size_t)svi * 64 + lane];
                float x1 = __uint_as_float(v << 16);
                float x2 = __uint_as_float(v & 0xffff0000u);
                s += q;
                acc1 = fmaf(q, x1, acc1);
                acc2 = fmaf(q, x2, acc2);
            }
        }
    }

    out[(size_t)node * 128 + lane]      = acc1 / s + b2[lane];
    out[(size_t)node * 128 + lane + 64] = acc2 / s + b2[lane + 64];
}

// ---------------- launch ----------------
extern "C" void kernel_launch(void* const* d_in, const int* in_sizes, int n_in,
                              void* d_out, int out_size, void* d_ws, size_t ws_size,
                              hipStream_t stream) {
    const float* x        = (const float*)d_in[0];
    const int*   src      = (const int*)d_in[1];
    const int*   dst      = (const int*)d_in[2];
    const float* W1       = (const float*)d_in[3];
    const float* att_src1 = (const float*)d_in[4];
    const float* att_dst1 = (const float*)d_in[5];
    const float* b1       = (const float*)d_in[6];
    const float* W2       = (const float*)d_in[7];
    const float* att_src2 = (const float*)d_in[8];
    const float* att_dst2 = (const float*)d_in[9];
    const float* b2       = (const float*)d_in[10];

    const int N = in_sizes[0] / 128;
    const int E = in_sizes[1];
    const int Etot = E + N;

    float* fws   = (float*)d_ws;
    float* asrc1 = fws;                    // N*8
    float* adst1 = asrc1 + (size_t)N * 8;  // N*8
    float* asrc2 = adst1 + (size_t)N * 8;  // N
    float* adst2 = asrc2 + N;              // N
    int*   deg     = (int*)(adst2 + N);    // N
    int*   cursor  = deg + N;              // N
    int*   row_ptr = cursor + N;           // N+1
    int*   col_src = row_ptr + N + 1;      // Etot
    int*   part    = col_src + Etot;       // <=1024
    unsigned* xhp  = (unsigned*)(part + 1024);  // N*64 packed bf16 pairs

    float* h = (float*)d_out;              // layer-1 output lives in d_out

    const int nodeBlocks = (N + 3) / 4;
    const int edgeBlocks = (Etot + 255) / 256;
    const int gemmBlocks = (N + 63) / 64;
    const int scanBlocks = (N + SCAN_BLOCK - 1) / SCAN_BLOCK;   // 196 <= 1024

    // CSR build (shared by both layers)
    zero_int_kernel<<<(2 * N + 255) / 256, 256, 0, stream>>>(deg, 2 * N);
    count_deg_kernel<<<edgeBlocks, 256, 0, stream>>>(dst, E, N, deg);
    deg_partial_kernel<<<scanBlocks, SCAN_BLOCK, 0, stream>>>(deg, part, N);
    scan_part_kernel<<<1, 1024, 0, stream>>>(part, scanBlocks);
    scan_final_kernel<<<scanBlocks, SCAN_BLOCK, 0, stream>>>(deg, part, row_ptr, N);
    scatter_kernel<<<edgeBlocks, 256, 0, stream>>>(src, dst, E, N, row_ptr, cursor, col_src);

    // Layer 1 (GEMM + fused attdot, packed-bf16 messages only)
    gemm_fused_kernel<<<gemmBlocks, 256, 0, stream>>>(x, W1, att_src1, att_dst1, xhp, asrc1, adst1, N, 8);
    agg1_kernel<<<nodeBlocks, 256, 0, stream>>>(xhp, asrc1, adst1, row_ptr, col_src, b1, h, N);

    // Layer 2
    gemm_fused_kernel<<<gemmBlocks, 256, 0, stream>>>(h, W2, att_src2, att_dst2, xhp, asrc2, adst2, N, 1);
    agg2_kernel<<<nodeBlocks, 256, 0, stream>>>(xhp, asrc2, adst2, row_ptr, col_src, b2, (float*)d_out, N);
}